// Round 16
// baseline (58.477 us; speedup 1.0000x reference)
//
#include <hip/hip_runtime.h>
#include <hip/hip_bf16.h>

// DEC ClusteringLayer: q[i][j] = (1/(1+||x_i-c_j||^2)) / rowsum, ALPHA=1.
// Round 16: 256x256 tile, 4-phase-per-K-step schedule (m201-style).
// 256 blocks (1/CU), 8 waves (2x4), wave tile 128x64, acc[8][4].
// Per K-step (32): 4 phases, each {a-frag ds_reads (+b in ph0) + staging duty;
// s_barrier; lgkmcnt(0); sched_barrier; setprio(1); 8 MFMA; setprio(0);
// s_barrier}. Duties: ph0 issue A(J+1) fp32->regs; ph1 issue B(J+1) glds;
// ph2 cvt+ds_write A(J+1) (compiler emits exact vmcnt for A-regs, B stays in
// flight); step-end barrier vmcnt(0) drains only the ~2.5-phase-old B DMA.

typedef __attribute__((ext_vector_type(8))) short short8v;
typedef __attribute__((ext_vector_type(4))) float f32x4;

#define DDIM 512
#define KCL  256
#define BM   256
#define NT   512
#define NSTEP 16
#define BTILE 8192       // shorts per fragment-order B image (256 x 32)

__device__ __forceinline__ short f2bf(float f) {
    __hip_bfloat16 h = __float2bfloat16(f);
    return __builtin_bit_cast(short, h);
}

__device__ __forceinline__ void glds16(const void* g, void* l) {
    __builtin_amdgcn_global_load_lds(
        (const __attribute__((address_space(1))) unsigned int*)g,
        (__attribute__((address_space(3))) unsigned int*)l, 16, 0, 0);
}

// ---- pre-kernel: blocks 0..63 pack clusters -> bf16 fragment-order images;
//      blocks 64..79 compute ||c||^2 ----
__global__ void prep(const float* __restrict__ cl, short* __restrict__ wsB,
                     float* __restrict__ wsC2) {
    const int t = threadIdx.x;
    if (blockIdx.x < 64) {
        const int u = blockIdx.x * 256 + t;
        const int img = u >> 10, gi = u & 1023;
        const int g = gi >> 6, lq = (gi >> 4) & 3, l15 = gi & 15;
        const float* src = cl + (size_t)(g * 16 + l15) * DDIM + img * 32 + lq * 8;
        float4 a = *(const float4*)src;
        float4 b = *(const float4*)(src + 4);
        short8v s;
        s[0]=f2bf(a.x); s[1]=f2bf(a.y); s[2]=f2bf(a.z); s[3]=f2bf(a.w);
        s[4]=f2bf(b.x); s[5]=f2bf(b.y); s[6]=f2bf(b.z); s[7]=f2bf(b.w);
        *(short8v*)&wsB[(size_t)u * 8] = s;
    } else {
        const int cidx = (blockIdx.x - 64) * 16 + (t >> 4);
        const int j = t & 15;
        const float* src = cl + (size_t)cidx * DDIM + j * 32;
        float s = 0.f;
#pragma unroll
        for (int i = 0; i < 8; ++i) {
            float4 v = ((const float4*)src)[i];
            s += v.x*v.x + v.y*v.y + v.z*v.z + v.w*v.w;
        }
        s += __shfl_xor(s, 1); s += __shfl_xor(s, 2);
        s += __shfl_xor(s, 4); s += __shfl_xor(s, 8);
        if (j == 0) wsC2[cidx] = s;
    }
}

#define SFENCE()   __builtin_amdgcn_sched_barrier(0)
#define PRIO1()    __builtin_amdgcn_s_setprio(1)
#define PRIO0()    __builtin_amdgcn_s_setprio(0)
#define BARSYNC()  asm volatile("s_barrier\ns_waitcnt lgkmcnt(0)" ::: "memory")
#define BARPOST()  __builtin_amdgcn_s_barrier()
#define BARVM0()   asm volatile("s_waitcnt vmcnt(0) lgkmcnt(0)\ns_barrier" ::: "memory")
#define BARLG()    asm volatile("s_waitcnt lgkmcnt(0)\ns_barrier" ::: "memory")

__global__ __launch_bounds__(NT, 2)
void dec_main(const float* __restrict__ x, const short* __restrict__ wsB,
              const float* __restrict__ wsC2, float* __restrict__ out) {
    __shared__ __align__(16) short lA[2][BTILE];   // 2 x 16 KB A (bf16 frag-order)
    __shared__ __align__(16) short lB[2][BTILE];   // 2 x 16 KB B images
    __shared__ float s_x2[BM];                     // 1 KB
    __shared__ float s_rs[4][BM];                  // 4 KB

    const int t = threadIdx.x, lane = t & 63, w = t >> 6;
    const int rg = w >> 2, cg = w & 3;             // 2 row-grp x 4 col-grp
    const int l15 = lane & 15, lq = lane >> 4;
    const int row0 = blockIdx.x * BM;

    // A staging: thread covers row t>>1, 16 floats at (t&1)*16 per K-step
    const float* xs = x + (size_t)(row0 + (t >> 1)) * DDIM + (t & 1) * 16;
    // fragment-order write slots (shorts): mb=t>>5, row15=(t>>1)&15, lq0=(t&1)*2
    const int awr0 = ((t >> 5) * 64 + (t & 1) * 32 + ((t >> 1) & 15)) * 8;
    const int awr1 = awr0 + 128;

    f32x4 acc[8][4];
#pragma unroll
    for (int m = 0; m < 8; ++m)
#pragma unroll
        for (int n = 0; n < 4; ++n) acc[m][n] = (f32x4){0.f,0.f,0.f,0.f};
    float x2p = 0.f;
    float4 A0, A1, A2, A3;     // A staging regs (16)

#define ALOAD(J)                                          \
    {  A0 = *(const float4*)(xs + (J) * 32);              \
       A1 = *(const float4*)(xs + (J) * 32 + 4);          \
       A2 = *(const float4*)(xs + (J) * 32 + 8);          \
       A3 = *(const float4*)(xs + (J) * 32 + 12); }

#define ACVT(J)                                                                  \
    {  short8v u_, v_;                                                           \
       u_[0]=f2bf(A0.x); u_[1]=f2bf(A0.y); u_[2]=f2bf(A0.z); u_[3]=f2bf(A0.w);   \
       u_[4]=f2bf(A1.x); u_[5]=f2bf(A1.y); u_[6]=f2bf(A1.z); u_[7]=f2bf(A1.w);   \
       v_[0]=f2bf(A2.x); v_[1]=f2bf(A2.y); v_[2]=f2bf(A2.z); v_[3]=f2bf(A2.w);   \
       v_[4]=f2bf(A3.x); v_[5]=f2bf(A3.y); v_[6]=f2bf(A3.z); v_[7]=f2bf(A3.w);   \
       x2p += A0.x*A0.x + A0.y*A0.y + A0.z*A0.z + A0.w*A0.w                      \
            + A1.x*A1.x + A1.y*A1.y + A1.z*A1.z + A1.w*A1.w                      \
            + A2.x*A2.x + A2.y*A2.y + A2.z*A2.z + A2.w*A2.w                      \
            + A3.x*A3.x + A3.y*A3.y + A3.z*A3.z + A3.w*A3.w;                     \
       *(short8v*)&lA[(J) & 1][awr0] = u_;                                       \
       *(short8v*)&lA[(J) & 1][awr1] = v_; }

#define BGLDS(J)                                                     \
    {  const short* s_ = wsB + (size_t)(J) * BTILE;                  \
       glds16(s_ + t * 8,        &lB[(J) & 1][t * 8]);               \
       glds16(s_ + 4096 + t * 8, &lB[(J) & 1][4096 + t * 8]); }

#define RD_A(J, M)  (*(const short8v*)&lA[(J) & 1][((rg*8 + (M))*64 + lane) * 8])
#define RD_B(J, N)  (*(const short8v*)&lB[(J) & 1][((cg*4 + (N))*512) + lane * 8])

#define MM(M, AF)                                                                \
    {  acc[M][0] = __builtin_amdgcn_mfma_f32_16x16x32_bf16(AF, b0_, acc[M][0], 0,0,0); \
       acc[M][1] = __builtin_amdgcn_mfma_f32_16x16x32_bf16(AF, b1_, acc[M][1], 0,0,0); \
       acc[M][2] = __builtin_amdgcn_mfma_f32_16x16x32_bf16(AF, b2_, acc[M][2], 0,0,0); \
       acc[M][3] = __builtin_amdgcn_mfma_f32_16x16x32_bf16(AF, b3_, acc[M][3], 0,0,0); }

#define STEP(J)                                                                  \
    {  /* phase 0: b-frags + a0,a1 ; issue A(J+1) */                             \
       short8v b0_ = RD_B(J,0), b1_ = RD_B(J,1), b2_ = RD_B(J,2), b3_ = RD_B(J,3);\
       short8v aP_ = RD_A(J,0), aQ_ = RD_A(J,1);                                 \
       if ((J) + 1 < NSTEP) { ALOAD((J)+1); }                                    \
       SFENCE(); BARSYNC(); SFENCE();                                            \
       PRIO1(); MM(0, aP_) MM(1, aQ_) PRIO0();                                   \
       BARPOST();                                                                \
       /* phase 1: a2,a3 ; issue B(J+1) DMA */                                   \
       aP_ = RD_A(J,2); aQ_ = RD_A(J,3);                                         \
       if ((J) + 1 < NSTEP) { BGLDS((J)+1); }                                    \
       SFENCE(); BARSYNC(); SFENCE();                                            \
       PRIO1(); MM(2, aP_) MM(3, aQ_) PRIO0();                                   \
       BARPOST();                                                                \
       /* phase 2: a4,a5 ; cvt+write A(J+1) (auto-vmcnt waits A-regs only) */    \
       aP_ = RD_A(J,4); aQ_ = RD_A(J,5);                                         \
       if ((J) + 1 < NSTEP) { ACVT((J)+1); }                                     \
       SFENCE(); BARSYNC(); SFENCE();                                            \
       PRIO1(); MM(4, aP_) MM(5, aQ_) PRIO0();                                   \
       BARPOST();                                                                \
       /* phase 3: a6,a7 ; step-end drain of B(J+1) DMA */                       \
       aP_ = RD_A(J,6); aQ_ = RD_A(J,7);                                         \
       SFENCE(); BARSYNC(); SFENCE();                                            \
       PRIO1(); MM(6, aP_) MM(7, aQ_) PRIO0();                                   \
       SFENCE();                                                                 \
       if ((J) + 1 < NSTEP) { BARVM0(); } else { BARLG(); }                      \
       SFENCE(); }

    // ---- prologue: A(0) regs->cvt->LDS, B(0) DMA, drain ----
    ALOAD(0);
    BGLDS(0);
    SFENCE();
    ACVT(0);                 // auto vmcnt(2): waits A-regs, leaves B DMA
    SFENCE();
    BARVM0();
    SFENCE();

    STEP( 0) STEP( 1) STEP( 2) STEP( 3)
    STEP( 4) STEP( 5) STEP( 6) STEP( 7)
    STEP( 8) STEP( 9) STEP(10) STEP(11)
    STEP(12) STEP(13) STEP(14) STEP(15)

    // ---- ||x||^2: pairs (t, t^1) share row t>>1 ----
    x2p += __shfl_xor(x2p, 1);
    if (!(t & 1)) s_x2[t >> 1] = x2p;
    __syncthreads();

    // ---- epilogue: d2 -> q_unnorm (C/D: col=l15, row=lq*4+r) ----
    float c2a[4];
#pragma unroll
    for (int n = 0; n < 4; ++n) c2a[n] = wsC2[cg*64 + n*16 + l15];

#pragma unroll
    for (int m = 0; m < 8; ++m)
#pragma unroll
        for (int n = 0; n < 4; ++n)
#pragma unroll
            for (int r = 0; r < 4; ++r) {
                const int rw = rg*128 + m*16 + lq*4 + r;
                float d2 = fmaxf(s_x2[rw] + c2a[n] - 2.0f * acc[m][n][r], 0.0f);
                acc[m][n][r] = 1.0f / (1.0f + d2);
            }

    // ---- row sums: 16-lane shuffle, per-cg slot (deterministic) ----
#pragma unroll
    for (int m = 0; m < 8; ++m)
#pragma unroll
        for (int r = 0; r < 4; ++r) {
            float p = acc[m][0][r] + acc[m][1][r] + acc[m][2][r] + acc[m][3][r];
            p += __shfl_xor(p, 1); p += __shfl_xor(p, 2);
            p += __shfl_xor(p, 4); p += __shfl_xor(p, 8);
            if (l15 == 0) s_rs[cg][rg*128 + m*16 + lq*4 + r] = p;
        }
    __syncthreads();

    // ---- normalize + store ----
#pragma unroll
    for (int m = 0; m < 8; ++m)
#pragma unroll
        for (int r = 0; r < 4; ++r) {
            const int rw = rg*128 + m*16 + lq*4 + r;
            const float rinv = 1.0f / (s_rs[0][rw] + s_rs[1][rw] + s_rs[2][rw] + s_rs[3][rw]);
            float* o = out + (size_t)(row0 + rw) * KCL + cg*64 + l15;
#pragma unroll
            for (int n = 0; n < 4; ++n)
                o[n * 16] = acc[m][n][r] * rinv;
        }
}

extern "C" void kernel_launch(void* const* d_in, const int* in_sizes, int n_in,
                              void* d_out, int out_size, void* d_ws, size_t ws_size,
                              hipStream_t stream) {
    const float* x  = (const float*)d_in[0];
    const float* cl = (const float*)d_in[1];
    float* out = (float*)d_out;
    short* wsB  = (short*)d_ws;
    float* wsC2 = (float*)((char*)d_ws + (size_t)NSTEP * BTILE * sizeof(short)); // +256 KB

    prep<<<80, 256, 0, stream>>>(cl, wsB, wsC2);
    const int B = in_sizes[0] / DDIM;     // 65536
    dec_main<<<B / BM, NT, 0, stream>>>(x, wsB, wsC2, out);
}